// Round 9
// baseline (316.466 us; speedup 1.0000x reference)
//
#include <hip/hip_runtime.h>
#include <hip/hip_bf16.h>

#define DIM 128
#define CHUNK 4096
#define CAP 4096        // slab capacity per 128-node bucket (65 sigma above mean)
typedef __hip_bfloat16 bf16;
typedef __attribute__((ext_vector_type(8))) short bf16x8;   // 8 bf16 = 4 VGPRs
typedef __attribute__((ext_vector_type(4))) float f32x4;

// ============================ K1: prep ======================================
__global__ void prep_kernel(int* __restrict__ bcursor, int nbuck,
                            const int* __restrict__ ei, int E, int* __restrict__ misc,
                            const float* __restrict__ W1, const float* __restrict__ W2,
                            bf16* __restrict__ Wsw1, bf16* __restrict__ Wsw2) {
    if (blockIdx.x == 0) {
        for (int i = threadIdx.x; i < nbuck; i += 256) bcursor[i] = i * CAP;
        if (threadIdx.x == 0) misc[2] = 0;          // scatter-done flag (re-zero each launch)
    } else if (blockIdx.x == 1) {
        __shared__ int s_or;
        if (threadIdx.x == 0) s_or = 0;
        __syncthreads();
        int lim = E < 16384 ? E : 16384;
        int acc = 0;
        for (int j = threadIdx.x; j < lim; j += 256) acc |= ei[2 * j + 1];
        if (acc) atomicOr(&s_or, 1);
        __syncthreads();
        if (threadIdx.x == 0) misc[1] = s_or;
    } else {
        // W f32 -> bf16 B-fragment order: frag f=kt*8+nt, lane l: n=l&15, k=(l>>4)*8+j
        int id = (blockIdx.x - 2) * 256 + threadIdx.x;       // 0..4095
        const float* W = (id < 2048) ? W1 : W2;
        bf16* Wsw = (id < 2048) ? Wsw1 : Wsw2;
        int t = id & 2047;
        int f = t >> 6, l = t & 63;
        int kt = f >> 3, nt = f & 7;
        int q = l >> 4, m = l & 15;
        bf16 tmp[8];
        #pragma unroll
        for (int j = 0; j < 8; ++j)
            tmp[j] = __float2bfloat16(W[(size_t)(kt * 32 + q * 8 + j) * DIM + nt * 16 + m]);
        *(bf16x8*)(Wsw + (size_t)t * 8) = *(const bf16x8*)tmp;
    }
}

// ============================ MFMA gemm1 ====================================
// Y[node][c] = bf16(X[node,:] @ W[:,c]); wave = 16 nodes x 128 cols.
// All 32 W fragments preloaded to registers (reused across ~4 tiles/wave).
__device__ __forceinline__ void gemm_body(const float* __restrict__ Xv,
                                          const bf16* __restrict__ Wsw,
                                          bf16* __restrict__ Y, int N,
                                          int gw, int nw, int lane,
                                          float* sld) {
    int m = lane & 15, q = lane >> 4;
    const bf16x8* bp = (const bf16x8*)Wsw;          // frag f at bp[f*64 + lane]
    bf16x8 wreg[32];
    #pragma unroll
    for (int f = 0; f < 32; ++f) wreg[f] = bp[(size_t)f * 64 + lane];
    for (int t = gw; t * 16 + 16 <= N; t += nw) {
        int base = t * 16;
        bf16x8 a[4];
        const float* xp = Xv + (size_t)(base + m) * DIM + q * 8;
        #pragma unroll
        for (int kt = 0; kt < 4; ++kt) {
            float4 v0 = *(const float4*)(xp + kt * 32);
            float4 v1 = *(const float4*)(xp + kt * 32 + 4);
            bf16 tt[8] = {__float2bfloat16(v0.x), __float2bfloat16(v0.y),
                          __float2bfloat16(v0.z), __float2bfloat16(v0.w),
                          __float2bfloat16(v1.x), __float2bfloat16(v1.y),
                          __float2bfloat16(v1.z), __float2bfloat16(v1.w)};
            a[kt] = *(const bf16x8*)tt;
        }
        f32x4 acc[8];
        #pragma unroll
        for (int nt = 0; nt < 8; ++nt) acc[nt] = (f32x4){0.f, 0.f, 0.f, 0.f};
        #pragma unroll
        for (int kt = 0; kt < 4; ++kt) {
            #pragma unroll
            for (int nt = 0; nt < 8; ++nt)
                acc[nt] = __builtin_amdgcn_mfma_f32_16x16x32_bf16(a[kt], wreg[kt * 8 + nt],
                                                                  acc[nt], 0, 0, 0);
        }
        // D: row (node) = q*4 + r, col (channel) = nt*16 + m
        #pragma unroll
        for (int nt = 0; nt < 8; ++nt)
            #pragma unroll
            for (int r = 0; r < 4; ++r)
                sld[(q * 4 + r) * 132 + nt * 16 + m] = acc[nt][r];
        asm volatile("s_waitcnt lgkmcnt(0)" ::: "memory");
        #pragma unroll
        for (int i = 0; i < 4; ++i) {
            int row = i * 4 + q;
            const float* rp = sld + row * 132 + m * 8;
            float4 v0 = *(const float4*)rp;
            float4 v1 = *(const float4*)(rp + 4);
            alignas(16) bf16 tt[8] = {
                __float2bfloat16(v0.x), __float2bfloat16(v0.y),
                __float2bfloat16(v0.z), __float2bfloat16(v0.w),
                __float2bfloat16(v1.x), __float2bfloat16(v1.y),
                __float2bfloat16(v1.z), __float2bfloat16(v1.w)};
            *(uint4*)(Y + (size_t)(base + row) * DIM + m * 8) = *(const uint4*)tt;
        }
        asm volatile("s_waitcnt lgkmcnt(0)" ::: "memory");
    }
}

// ================== K2: scatter || gemm1 || bucket_sort =====================
// blocks [0,nchunks): slab scatter; each chunk releases its staged writes with
//   __threadfence() then atomicAdd(misc[2]).
// blocks [nchunks, nchunks+NG): gemm1.
// blocks [nchunks+NG, ...): per-bucket counting sort; spins (acquire) until
//   misc[2]==nchunks. Deadlock-free: scatter blocks precede sort blocks in
//   dispatch order and never wait, so the flag always completes.
__global__ __launch_bounds__(256)
void scatter_gemm1_sort(const int* __restrict__ ei, int E, int* __restrict__ misc,
                        int* __restrict__ bcursor, unsigned* __restrict__ staged,
                        int nbuck, int nchunks, int ngemm,
                        const float* __restrict__ X, const bf16* __restrict__ Wsw,
                        bf16* __restrict__ Y,
                        int* __restrict__ csr, int* __restrict__ rowstart,
                        int* __restrict__ cnt, float* __restrict__ dis, int N) {
    __shared__ float smem[4][16 * 132];             // 33.8 KB; scatter/sort alias it
    int bx = blockIdx.x;
    int tid = threadIdx.x;
    if (bx < nchunks) {
        int* s_cnt  = (int*)&smem[0][0];
        int* s_base = s_cnt + 512;
        int* s_fill = s_cnt + 1024;
        for (int i = tid; i < nbuck; i += 256) { s_cnt[i] = 0; s_fill[i] = 0; }
        __syncthreads();
        int flagI = misc[1];
        int c0 = bx * CHUNK;
        int cn = min(E - c0, CHUNK);
        for (int i = tid; i < cn; i += 256) {
            int e = c0 + i;
            int d = (flagI == 0) ? ei[2 * E + 2 * e] : ei[E + e];
            atomicAdd(&s_cnt[d >> 7], 1);
        }
        __syncthreads();
        for (int i = tid; i < nbuck; i += 256) {
            int c = s_cnt[i];
            s_base[i] = c ? atomicAdd(&bcursor[i], c) : 0;
        }
        __syncthreads();
        for (int i = tid; i < cn; i += 256) {
            int e = c0 + i;
            int s, d;
            if (flagI == 0) { s = ei[2 * e]; d = ei[2 * E + 2 * e]; }
            else            { s = ei[e];     d = ei[E + e]; }
            int b = d >> 7;
            int r = s_base[b] + atomicAdd(&s_fill[b], 1);
            if (r < (b + 1) * CAP)                           // overflow clamp (never hit)
                staged[r] = ((unsigned)s << 7) | (unsigned)(d & 127);
        }
        __syncthreads();
        __threadfence();                                     // release staged/bcursor
        if (tid == 0) atomicAdd(&misc[2], 1);
    } else if (bx < nchunks + ngemm) {
        int wid = tid >> 6, lane = tid & 63;
        int ngw = ngemm * 4;
        gemm_body(X, Wsw, Y, N, (bx - nchunks - 0) * 4 + wid, ngw, lane, smem[wid]);
    } else {
        // ---- bucket sort (waits for all scatter chunks) ----
        if (tid == 0) {
            while (__hip_atomic_load(&misc[2], __ATOMIC_ACQUIRE,
                                     __HIP_MEMORY_SCOPE_AGENT) < nchunks)
                __builtin_amdgcn_s_sleep(8);
        }
        __syncthreads();
        int* s_cnt  = (int*)&smem[0][0];
        int* s_off  = s_cnt + 128;
        int* s_fill = s_cnt + 256;
        int* s_scan = s_cnt + 384;
        int b = bx - nchunks - ngemm;
        int seg0 = b * CAP;
        int n = min(bcursor[b] - seg0, CAP);
        if (tid < 128) { s_cnt[tid] = 0; s_fill[tid] = 0; }
        __syncthreads();
        for (int i = tid; i < n; i += 256)
            atomicAdd(&s_cnt[staged[seg0 + i] & 127u], 1);
        __syncthreads();
        int v = (tid < 128) ? s_cnt[tid] : 0;
        if (tid < 128) s_scan[tid] = v;
        __syncthreads();
        for (int off = 1; off < 128; off <<= 1) {
            int t = (tid < 128 && tid >= off) ? s_scan[tid - off] : 0;
            __syncthreads();
            if (tid < 128) s_scan[tid] += t;
            __syncthreads();
        }
        if (tid < 128) {
            s_off[tid] = s_scan[tid] - v;
            int node = b * 128 + tid;
            if (node < N) {
                cnt[node] = v;
                rowstart[node] = seg0 + s_off[tid];
                dis[node] = rsqrtf((float)(v + 1));   // +1 self loop
            }
        }
        __syncthreads();
        for (int i = tid; i < n; i += 256) {
            unsigned p = staged[seg0 + i];
            int dl = p & 127u;
            int r = atomicAdd(&s_fill[dl], 1);
            csr[seg0 + s_off[dl] + r] = (int)(p >> 7);
        }
    }
}

// ============================ helpers =======================================
__device__ __forceinline__ void fma8(float* a, uint4 v, float ds) {
    a[0] = fmaf(__uint_as_float(v.x << 16), ds, a[0]);
    a[1] = fmaf(__uint_as_float(v.x & 0xffff0000u), ds, a[1]);
    a[2] = fmaf(__uint_as_float(v.y << 16), ds, a[2]);
    a[3] = fmaf(__uint_as_float(v.y & 0xffff0000u), ds, a[3]);
    a[4] = fmaf(__uint_as_float(v.z << 16), ds, a[4]);
    a[5] = fmaf(__uint_as_float(v.z & 0xffff0000u), ds, a[5]);
    a[6] = fmaf(__uint_as_float(v.w << 16), ds, a[6]);
    a[7] = fmaf(__uint_as_float(v.w & 0xffff0000u), ds, a[7]);
}

__device__ __forceinline__ void add8(float* a, uint4 v) {
    a[0] += __uint_as_float(v.x << 16);
    a[1] += __uint_as_float(v.x & 0xffff0000u);
    a[2] += __uint_as_float(v.y << 16);
    a[3] += __uint_as_float(v.y & 0xffff0000u);
    a[4] += __uint_as_float(v.z << 16);
    a[5] += __uint_as_float(v.z & 0xffff0000u);
    a[6] += __uint_as_float(v.w << 16);
    a[7] += __uint_as_float(v.w & 0xffff0000u);
}

// ================= K4: aggregate1 + gemm2 (fused, pre-scaled out) ===========
__global__ __launch_bounds__(256, 4)
void agg1_gemm2(const uint4* __restrict__ Y, const int* __restrict__ rowstart,
                const int* __restrict__ cnt, const int* __restrict__ csr,
                const float* __restrict__ dis, const float* __restrict__ bias,
                const bf16* __restrict__ Wsw, bf16* __restrict__ Y2, int N) {
    __shared__ __align__(16) bf16 h_lds[16][136];   // row stride 272B = 17x16B
    __shared__ float s_out[16 * 132];
    int wave = threadIdx.x >> 6, lane = threadIdx.x & 63;
    int sub = lane >> 4, cl = lane & 15;
    int base = blockIdx.x * 16;
    int node = base + wave * 4 + sub;
    bool alive = node < N;

    // ---- Phase A ----
    float acc[4][8];
    #pragma unroll
    for (int j = 0; j < 4; ++j)
        #pragma unroll
        for (int k = 0; k < 8; ++k) acc[j][k] = 0.f;

    float dn = 0.f;
    if (alive) {
        int e0 = rowstart[node], e1 = e0 + cnt[node];
        dn = dis[node];
        fma8(acc[3], Y[(size_t)node * 16 + cl], dn);        // self loop

        int e = e0;
        while (e + 8 <= e1) {
            int s[8];
            #pragma unroll
            for (int j = 0; j < 8; ++j) s[j] = csr[e + j];
            uint4 v[8]; float dv[8];
            #pragma unroll
            for (int j = 0; j < 8; ++j) { v[j] = Y[(size_t)s[j] * 16 + cl]; dv[j] = dis[s[j]]; }
            #pragma unroll
            for (int j = 0; j < 8; ++j) fma8(acc[j & 3], v[j], dv[j]);
            e += 8;
        }
        if (e + 4 <= e1) {
            int s[4];
            #pragma unroll
            for (int j = 0; j < 4; ++j) s[j] = csr[e + j];
            uint4 v[4]; float dv[4];
            #pragma unroll
            for (int j = 0; j < 4; ++j) { v[j] = Y[(size_t)s[j] * 16 + cl]; dv[j] = dis[s[j]]; }
            #pragma unroll
            for (int j = 0; j < 4; ++j) fma8(acc[j], v[j], dv[j]);
            e += 4;
        }
        for (; e < e1; ++e) {
            int s = csr[e];
            fma8(acc[0], Y[(size_t)s * 16 + cl], dis[s]);
        }
    }
    {
        float s8[8];
        #pragma unroll
        for (int k = 0; k < 8; ++k)
            s8[k] = (acc[0][k] + acc[1][k]) + (acc[2][k] + acc[3][k]);
        float4 b0 = ((const float4*)bias)[2 * cl];
        float4 b1 = ((const float4*)bias)[2 * cl + 1];
        alignas(16) bf16 t[8];
        t[0] = __float2bfloat16(alive ? fmaxf(dn * s8[0] + b0.x, 0.f) : 0.f);
        t[1] = __float2bfloat16(alive ? fmaxf(dn * s8[1] + b0.y, 0.f) : 0.f);
        t[2] = __float2bfloat16(alive ? fmaxf(dn * s8[2] + b0.z, 0.f) : 0.f);
        t[3] = __float2bfloat16(alive ? fmaxf(dn * s8[3] + b0.w, 0.f) : 0.f);
        t[4] = __float2bfloat16(alive ? fmaxf(dn * s8[4] + b1.x, 0.f) : 0.f);
        t[5] = __float2bfloat16(alive ? fmaxf(dn * s8[5] + b1.y, 0.f) : 0.f);
        t[6] = __float2bfloat16(alive ? fmaxf(dn * s8[6] + b1.z, 0.f) : 0.f);
        t[7] = __float2bfloat16(alive ? fmaxf(dn * s8[7] + b1.w, 0.f) : 0.f);
        *(uint4*)&h_lds[wave * 4 + sub][cl * 8] = *(const uint4*)t;
    }
    __syncthreads();

    // ---- Phase B: 16x128 @ 128x128 MFMA; wave handles nt = {wave*2, wave*2+1} ----
    int m = cl, q = sub;
    bf16x8 a[4];
    #pragma unroll
    for (int kt = 0; kt < 4; ++kt)
        a[kt] = *(const bf16x8*)&h_lds[m][q * 8 + kt * 32];
    const bf16x8* bp = (const bf16x8*)Wsw;
    f32x4 g[2];
    g[0] = (f32x4){0.f, 0.f, 0.f, 0.f};
    g[1] = (f32x4){0.f, 0.f, 0.f, 0.f};
    #pragma unroll
    for (int kt = 0; kt < 4; ++kt) {
        #pragma unroll
        for (int j = 0; j < 2; ++j) {
            int nt = wave * 2 + j;
            bf16x8 bfr = bp[(size_t)(kt * 8 + nt) * 64 + lane];
            g[j] = __builtin_amdgcn_mfma_f32_16x16x32_bf16(a[kt], bfr, g[j], 0, 0, 0);
        }
    }
    #pragma unroll
    for (int j = 0; j < 2; ++j)
        #pragma unroll
        for (int r = 0; r < 4; ++r)
            s_out[(q * 4 + r) * 132 + (wave * 2 + j) * 16 + m] = g[j][r];
    __syncthreads();

    // ---- Phase C: coalesced, dis-pre-scaled bf16 store ----
    int on = threadIdx.x >> 4;
    int oc = (threadIdx.x & 15) * 8;
    if (base + on < N) {
        float ds = dis[base + on];
        const float* rp = s_out + on * 132 + oc;
        float4 v0 = *(const float4*)rp;
        float4 v1 = *(const float4*)(rp + 4);
        alignas(16) bf16 t[8] = {
            __float2bfloat16(v0.x * ds), __float2bfloat16(v0.y * ds),
            __float2bfloat16(v0.z * ds), __float2bfloat16(v0.w * ds),
            __float2bfloat16(v1.x * ds), __float2bfloat16(v1.y * ds),
            __float2bfloat16(v1.z * ds), __float2bfloat16(v1.w * ds)};
        *(uint4*)(Y2 + (size_t)(base + on) * DIM + oc) = *(const uint4*)t;
    }
}

// ================= K5: final aggregate (inputs pre-scaled) ==================
__global__ __launch_bounds__(256, 4)
void aggregate_final(const uint4* __restrict__ Y, const int* __restrict__ rowstart,
                     const int* __restrict__ cnt, const int* __restrict__ csr,
                     const float* __restrict__ dis, const float* __restrict__ bias,
                     float* __restrict__ Of, int N) {
    int wave = threadIdx.x >> 6;
    int lane = threadIdx.x & 63;
    int sub = lane >> 4, cl = lane & 15;
    int node = blockIdx.x * 16 + wave * 4 + sub;
    if (node >= N) return;
    int e0 = rowstart[node], e1 = e0 + cnt[node];

    float acc[4][8];
    #pragma unroll
    for (int j = 0; j < 4; ++j)
        #pragma unroll
        for (int k = 0; k < 8; ++k) acc[j][k] = 0.f;

    float dn = dis[node];
    add8(acc[3], Y[(size_t)node * 16 + cl]);            // self loop (pre-scaled)

    int e = e0;
    while (e + 12 <= e1) {
        int s[12];
        #pragma unroll
        for (int j = 0; j < 12; ++j) s[j] = csr[e + j];
        uint4 v[12];
        #pragma unroll
        for (int j = 0; j < 12; ++j) v[j] = Y[(size_t)s[j] * 16 + cl];
        #pragma unroll
        for (int j = 0; j < 12; ++j) add8(acc[j & 3], v[j]);
        e += 12;
    }
    if (e + 8 <= e1) {
        int s[8];
        #pragma unroll
        for (int j = 0; j < 8; ++j) s[j] = csr[e + j];
        uint4 v[8];
        #pragma unroll
        for (int j = 0; j < 8; ++j) v[j] = Y[(size_t)s[j] * 16 + cl];
        #pragma unroll
        for (int j = 0; j < 8; ++j) add8(acc[j & 3], v[j]);
        e += 8;
    }
    if (e + 4 <= e1) {
        int s[4];
        #pragma unroll
        for (int j = 0; j < 4; ++j) s[j] = csr[e + j];
        uint4 v[4];
        #pragma unroll
        for (int j = 0; j < 4; ++j) v[j] = Y[(size_t)s[j] * 16 + cl];
        #pragma unroll
        for (int j = 0; j < 4; ++j) add8(acc[j], v[j]);
        e += 4;
    }
    for (; e < e1; ++e)
        add8(acc[0], Y[(size_t)csr[e] * 16 + cl]);

    float s8[8];
    #pragma unroll
    for (int k = 0; k < 8; ++k)
        s8[k] = (acc[0][k] + acc[1][k]) + (acc[2][k] + acc[3][k]);

    float4 b0 = ((const float4*)bias)[2 * cl];
    float4 b1 = ((const float4*)bias)[2 * cl + 1];
    f32x4 o0, o1;
    o0[0] = fmaxf(dn * s8[0] + b0.x, 0.f);
    o0[1] = fmaxf(dn * s8[1] + b0.y, 0.f);
    o0[2] = fmaxf(dn * s8[2] + b0.z, 0.f);
    o0[3] = fmaxf(dn * s8[3] + b0.w, 0.f);
    o1[0] = fmaxf(dn * s8[4] + b1.x, 0.f);
    o1[1] = fmaxf(dn * s8[5] + b1.y, 0.f);
    o1[2] = fmaxf(dn * s8[6] + b1.z, 0.f);
    o1[3] = fmaxf(dn * s8[7] + b1.w, 0.f);
    // Output is never re-read: nontemporal keeps L2 clean for the Y2' gathers.
    f32x4* op = (f32x4*)(Of + (size_t)node * DIM + cl * 8);
    __builtin_nontemporal_store(o0, op);
    __builtin_nontemporal_store(o1, op + 1);
}

// ============================ launcher ======================================
extern "C" void kernel_launch(void* const* d_in, const int* in_sizes, int n_in,
                              void* d_out, int out_size, void* d_ws, size_t ws_size,
                              hipStream_t stream) {
    const float* x  = (const float*)d_in[0];
    const int*   ei = (const int*)d_in[1];
    const float* W1 = (const float*)d_in[2];
    const float* b1 = (const float*)d_in[3];
    const float* W2 = (const float*)d_in[4];
    const float* b2 = (const float*)d_in[5];

    int N = in_sizes[0] / DIM;      // 50000
    int E = in_sizes[1] / 2;        // 600000
    int nbuck = (N + 127) / 128;    // 391
    int nchunks = (E + CHUNK - 1) / CHUNK;  // 147
    int ngemm = 196;                // ~4 tiles/wave; W stays register-resident

    char* w = (char*)d_ws;
    size_t used = 0;
    auto carve = [&](size_t bytes) {
        char* p = w + used;
        used += (bytes + 255) & ~(size_t)255;
        return p;
    };
    int*      misc     = (int*)     carve(256);              // [1]=flagI [2]=done
    int*      bcursor  = (int*)     carve((size_t)(nbuck + 1) * 4);
    unsigned* staged   = (unsigned*)carve((size_t)nbuck * CAP * 4);   // 6.4 MB
    int*      csr      = (int*)     carve((size_t)nbuck * CAP * 4);   // 6.4 MB
    int*      rowstart = (int*)     carve((size_t)N * 4);
    int*      cnt      = (int*)     carve((size_t)N * 4);
    float*    dis      = (float*)   carve((size_t)N * 4);
    bf16*     ybuf     = (bf16*)    carve((size_t)N * DIM * 2);       // Y1
    bf16*     hbuf     = (bf16*)    carve((size_t)N * DIM * 2);       // Y2' (pre-scaled)
    bf16*     Wsw1     = (bf16*)    carve((size_t)DIM * DIM * 2);
    bf16*     Wsw2     = (bf16*)    carve((size_t)DIM * DIM * 2);

    prep_kernel <<<18, 256, 0, stream>>>(bcursor, nbuck, ei, E, misc, W1, W2, Wsw1, Wsw2);
    scatter_gemm1_sort<<<nchunks + ngemm + nbuck, 256, 0, stream>>>(
        ei, E, misc, bcursor, staged, nbuck, nchunks, ngemm,
        x, Wsw1, ybuf, csr, rowstart, cnt, dis, N);

    int ablocks = (N + 15) / 16;            // 3125
    agg1_gemm2<<<ablocks, 256, 0, stream>>>((const uint4*)ybuf, rowstart, cnt, csr,
                                            dis, b1, Wsw2, hbuf, N);
    aggregate_final<<<ablocks, 256, 0, stream>>>((const uint4*)hbuf, rowstart, cnt, csr,
                                                 dis, b2, (float*)d_out, N);
}

// Round 10
// 178.931 us; speedup vs baseline: 1.7686x; 1.7686x over previous
//
#include <hip/hip_runtime.h>
#include <hip/hip_bf16.h>

#define DIM 128
#define CHUNK 4096
#define CAP 4096        // slab capacity per 128-node bucket (65 sigma above mean)
typedef __hip_bfloat16 bf16;
typedef __attribute__((ext_vector_type(8))) short bf16x8;   // 8 bf16 = 4 VGPRs
typedef __attribute__((ext_vector_type(4))) float f32x4;

// ============================ K1: prep ======================================
__global__ void prep_kernel(int* __restrict__ bcursor, int nbuck,
                            const int* __restrict__ ei, int E, int* __restrict__ misc,
                            const float* __restrict__ W1, const float* __restrict__ W2,
                            bf16* __restrict__ Wsw1, bf16* __restrict__ Wsw2) {
    if (blockIdx.x == 0) {
        for (int i = threadIdx.x; i < nbuck; i += 256) bcursor[i] = i * CAP;
    } else if (blockIdx.x == 1) {
        __shared__ int s_or;
        if (threadIdx.x == 0) s_or = 0;
        __syncthreads();
        int lim = E < 16384 ? E : 16384;
        int acc = 0;
        for (int j = threadIdx.x; j < lim; j += 256) acc |= ei[2 * j + 1];
        if (acc) atomicOr(&s_or, 1);
        __syncthreads();
        if (threadIdx.x == 0) misc[1] = s_or;
    } else {
        // W f32 -> bf16 B-fragment order: frag f=kt*8+nt, lane l: n=l&15, k=(l>>4)*8+j
        int id = (blockIdx.x - 2) * 256 + threadIdx.x;       // 0..4095
        const float* W = (id < 2048) ? W1 : W2;
        bf16* Wsw = (id < 2048) ? Wsw1 : Wsw2;
        int t = id & 2047;
        int f = t >> 6, l = t & 63;
        int kt = f >> 3, nt = f & 7;
        int q = l >> 4, m = l & 15;
        bf16 tmp[8];
        #pragma unroll
        for (int j = 0; j < 8; ++j)
            tmp[j] = __float2bfloat16(W[(size_t)(kt * 32 + q * 8 + j) * DIM + nt * 16 + m]);
        *(bf16x8*)(Wsw + (size_t)t * 8) = *(const bf16x8*)tmp;
    }
}

// ============================ MFMA gemm1 ====================================
// Y[node][c] = bf16(X[node,:] @ W[:,c]); wave = 16 nodes x 128 cols.
// All 32 W fragments preloaded to registers (reused across ~4 tiles/wave).
// Epilogue: stage f32 acc through per-wave LDS tile [16][132], read back
// row-major, emit 4x dwordx4 coalesced stores.
__device__ __forceinline__ void gemm_body(const float* __restrict__ Xv,
                                          const bf16* __restrict__ Wsw,
                                          bf16* __restrict__ Y, int N,
                                          int gw, int nw, int lane,
                                          float* sld) {
    int m = lane & 15, q = lane >> 4;
    const bf16x8* bp = (const bf16x8*)Wsw;          // frag f at bp[f*64 + lane]
    bf16x8 wreg[32];
    #pragma unroll
    for (int f = 0; f < 32; ++f) wreg[f] = bp[(size_t)f * 64 + lane];
    for (int t = gw; t * 16 + 16 <= N; t += nw) {
        int base = t * 16;
        bf16x8 a[4];
        const float* xp = Xv + (size_t)(base + m) * DIM + q * 8;
        #pragma unroll
        for (int kt = 0; kt < 4; ++kt) {
            float4 v0 = *(const float4*)(xp + kt * 32);
            float4 v1 = *(const float4*)(xp + kt * 32 + 4);
            bf16 tt[8] = {__float2bfloat16(v0.x), __float2bfloat16(v0.y),
                          __float2bfloat16(v0.z), __float2bfloat16(v0.w),
                          __float2bfloat16(v1.x), __float2bfloat16(v1.y),
                          __float2bfloat16(v1.z), __float2bfloat16(v1.w)};
            a[kt] = *(const bf16x8*)tt;
        }
        f32x4 acc[8];
        #pragma unroll
        for (int nt = 0; nt < 8; ++nt) acc[nt] = (f32x4){0.f, 0.f, 0.f, 0.f};
        #pragma unroll
        for (int kt = 0; kt < 4; ++kt) {
            #pragma unroll
            for (int nt = 0; nt < 8; ++nt)
                acc[nt] = __builtin_amdgcn_mfma_f32_16x16x32_bf16(a[kt], wreg[kt * 8 + nt],
                                                                  acc[nt], 0, 0, 0);
        }
        // D: row (node) = q*4 + r, col (channel) = nt*16 + m
        #pragma unroll
        for (int nt = 0; nt < 8; ++nt)
            #pragma unroll
            for (int r = 0; r < 4; ++r)
                sld[(q * 4 + r) * 132 + nt * 16 + m] = acc[nt][r];
        asm volatile("s_waitcnt lgkmcnt(0)" ::: "memory");
        #pragma unroll
        for (int i = 0; i < 4; ++i) {
            int row = i * 4 + q;
            const float* rp = sld + row * 132 + m * 8;
            float4 v0 = *(const float4*)rp;
            float4 v1 = *(const float4*)(rp + 4);
            alignas(16) bf16 tt[8] = {
                __float2bfloat16(v0.x), __float2bfloat16(v0.y),
                __float2bfloat16(v0.z), __float2bfloat16(v0.w),
                __float2bfloat16(v1.x), __float2bfloat16(v1.y),
                __float2bfloat16(v1.z), __float2bfloat16(v1.w)};
            *(uint4*)(Y + (size_t)(base + row) * DIM + m * 8) = *(const uint4*)tt;
        }
        asm volatile("s_waitcnt lgkmcnt(0)" ::: "memory");
    }
}

// ============================ K2: scatter || gemm1 ==========================
__global__ __launch_bounds__(256)
void scatter_gemm1(const int* __restrict__ ei, int E, const int* __restrict__ misc,
                   int* __restrict__ bcursor, unsigned* __restrict__ staged,
                   int nbuck, int nchunks,
                   const float* __restrict__ X, const bf16* __restrict__ Wsw,
                   bf16* __restrict__ Y, int N) {
    __shared__ float smem[4][16 * 132];             // 33.8 KB; scatter aliases it
    int bx = blockIdx.x;
    if (bx < nchunks) {
        int* s_cnt  = (int*)&smem[0][0];
        int* s_base = s_cnt + 512;
        int* s_fill = s_cnt + 1024;
        for (int i = threadIdx.x; i < nbuck; i += 256) { s_cnt[i] = 0; s_fill[i] = 0; }
        __syncthreads();
        int flagI = misc[1];
        int c0 = bx * CHUNK;
        int cn = min(E - c0, CHUNK);
        for (int i = threadIdx.x; i < cn; i += 256) {
            int e = c0 + i;
            int d = (flagI == 0) ? ei[2 * E + 2 * e] : ei[E + e];
            atomicAdd(&s_cnt[d >> 7], 1);
        }
        __syncthreads();
        for (int i = threadIdx.x; i < nbuck; i += 256) {
            int c = s_cnt[i];
            s_base[i] = c ? atomicAdd(&bcursor[i], c) : 0;
        }
        __syncthreads();
        for (int i = threadIdx.x; i < cn; i += 256) {
            int e = c0 + i;
            int s, d;
            if (flagI == 0) { s = ei[2 * e]; d = ei[2 * E + 2 * e]; }
            else            { s = ei[e];     d = ei[E + e]; }
            int b = d >> 7;
            int r = s_base[b] + atomicAdd(&s_fill[b], 1);
            if (r < (b + 1) * CAP)                           // overflow clamp (never hit)
                staged[r] = ((unsigned)s << 7) | (unsigned)(d & 127);
        }
    } else {
        int wid = threadIdx.x >> 6, lane = threadIdx.x & 63;
        int ngw = (gridDim.x - nchunks) * 4;
        gemm_body(X, Wsw, Y, N, (bx - nchunks) * 4 + wid, ngw, lane, smem[wid]);
    }
}

// ================ K3: within-bucket sort + dis ==============================
__global__ void bucket_sort(const unsigned* __restrict__ staged,
                            const int* __restrict__ bcursor,
                            int* __restrict__ csr, int* __restrict__ rowstart,
                            int* __restrict__ cnt, float* __restrict__ dis, int N) {
    __shared__ int s_cnt[128], s_off[128], s_fill[128], s_scan[128];
    int b = blockIdx.x, tid = threadIdx.x;
    int seg0 = b * CAP;
    int n = min(bcursor[b] - seg0, CAP);
    if (tid < 128) { s_cnt[tid] = 0; s_fill[tid] = 0; }
    __syncthreads();
    for (int i = tid; i < n; i += 256)
        atomicAdd(&s_cnt[staged[seg0 + i] & 127u], 1);
    __syncthreads();
    int v = (tid < 128) ? s_cnt[tid] : 0;
    if (tid < 128) s_scan[tid] = v;
    __syncthreads();
    for (int off = 1; off < 128; off <<= 1) {
        int t = (tid < 128 && tid >= off) ? s_scan[tid - off] : 0;
        __syncthreads();
        if (tid < 128) s_scan[tid] += t;
        __syncthreads();
    }
    if (tid < 128) {
        s_off[tid] = s_scan[tid] - v;
        int node = b * 128 + tid;
        if (node < N) {
            cnt[node] = v;
            rowstart[node] = seg0 + s_off[tid];
            dis[node] = rsqrtf((float)(v + 1));   // +1 self loop
        }
    }
    __syncthreads();
    for (int i = tid; i < n; i += 256) {
        unsigned p = staged[seg0 + i];
        int dl = p & 127u;
        int r = atomicAdd(&s_fill[dl], 1);
        csr[seg0 + s_off[dl] + r] = (int)(p >> 7);
    }
}

// ============================ helpers =======================================
__device__ __forceinline__ void fma8(float* a, uint4 v, float ds) {
    a[0] = fmaf(__uint_as_float(v.x << 16), ds, a[0]);
    a[1] = fmaf(__uint_as_float(v.x & 0xffff0000u), ds, a[1]);
    a[2] = fmaf(__uint_as_float(v.y << 16), ds, a[2]);
    a[3] = fmaf(__uint_as_float(v.y & 0xffff0000u), ds, a[3]);
    a[4] = fmaf(__uint_as_float(v.z << 16), ds, a[4]);
    a[5] = fmaf(__uint_as_float(v.z & 0xffff0000u), ds, a[5]);
    a[6] = fmaf(__uint_as_float(v.w << 16), ds, a[6]);
    a[7] = fmaf(__uint_as_float(v.w & 0xffff0000u), ds, a[7]);
}

__device__ __forceinline__ void add8(float* a, uint4 v) {
    a[0] += __uint_as_float(v.x << 16);
    a[1] += __uint_as_float(v.x & 0xffff0000u);
    a[2] += __uint_as_float(v.y << 16);
    a[3] += __uint_as_float(v.y & 0xffff0000u);
    a[4] += __uint_as_float(v.z << 16);
    a[5] += __uint_as_float(v.z & 0xffff0000u);
    a[6] += __uint_as_float(v.w << 16);
    a[7] += __uint_as_float(v.w & 0xffff0000u);
}

// ================= K4: aggregate1 + gemm2 (fused, pre-scaled out) ===========
// Phase A: h[n] = relu(dn*(Y1[n]*dn + sum Y1[s]*ds) + b1)  -> LDS (never global)
// Phase B: per-block 16x128 @ 128x128 MFMA on LDS h-tile
// Phase C: Y2'[n][c] = bf16( (h@W2)[n][c] * dis[n] )  -> coalesced store
__global__ __launch_bounds__(256, 4)
void agg1_gemm2(const uint4* __restrict__ Y, const int* __restrict__ rowstart,
                const int* __restrict__ cnt, const int* __restrict__ csr,
                const float* __restrict__ dis, const float* __restrict__ bias,
                const bf16* __restrict__ Wsw, bf16* __restrict__ Y2, int N) {
    __shared__ __align__(16) bf16 h_lds[16][136];   // row stride 272B = 17x16B
    __shared__ float s_out[16 * 132];
    int wave = threadIdx.x >> 6, lane = threadIdx.x & 63;
    int sub = lane >> 4, cl = lane & 15;
    int base = blockIdx.x * 16;
    int node = base + wave * 4 + sub;
    bool alive = node < N;

    // ---- Phase A ----
    float acc[4][8];
    #pragma unroll
    for (int j = 0; j < 4; ++j)
        #pragma unroll
        for (int k = 0; k < 8; ++k) acc[j][k] = 0.f;

    float dn = 0.f;
    if (alive) {
        int e0 = rowstart[node], e1 = e0 + cnt[node];
        dn = dis[node];
        fma8(acc[3], Y[(size_t)node * 16 + cl], dn);        // self loop

        int e = e0;
        while (e + 8 <= e1) {
            int s[8];
            #pragma unroll
            for (int j = 0; j < 8; ++j) s[j] = csr[e + j];
            uint4 v[8]; float dv[8];
            #pragma unroll
            for (int j = 0; j < 8; ++j) { v[j] = Y[(size_t)s[j] * 16 + cl]; dv[j] = dis[s[j]]; }
            #pragma unroll
            for (int j = 0; j < 8; ++j) fma8(acc[j & 3], v[j], dv[j]);
            e += 8;
        }
        if (e + 4 <= e1) {
            int s[4];
            #pragma unroll
            for (int j = 0; j < 4; ++j) s[j] = csr[e + j];
            uint4 v[4]; float dv[4];
            #pragma unroll
            for (int j = 0; j < 4; ++j) { v[j] = Y[(size_t)s[j] * 16 + cl]; dv[j] = dis[s[j]]; }
            #pragma unroll
            for (int j = 0; j < 4; ++j) fma8(acc[j], v[j], dv[j]);
            e += 4;
        }
        for (; e < e1; ++e) {
            int s = csr[e];
            fma8(acc[0], Y[(size_t)s * 16 + cl], dis[s]);
        }
    }
    {
        float s8[8];
        #pragma unroll
        for (int k = 0; k < 8; ++k)
            s8[k] = (acc[0][k] + acc[1][k]) + (acc[2][k] + acc[3][k]);
        float4 b0 = ((const float4*)bias)[2 * cl];
        float4 b1 = ((const float4*)bias)[2 * cl + 1];
        alignas(16) bf16 t[8];
        t[0] = __float2bfloat16(alive ? fmaxf(dn * s8[0] + b0.x, 0.f) : 0.f);
        t[1] = __float2bfloat16(alive ? fmaxf(dn * s8[1] + b0.y, 0.f) : 0.f);
        t[2] = __float2bfloat16(alive ? fmaxf(dn * s8[2] + b0.z, 0.f) : 0.f);
        t[3] = __float2bfloat16(alive ? fmaxf(dn * s8[3] + b0.w, 0.f) : 0.f);
        t[4] = __float2bfloat16(alive ? fmaxf(dn * s8[4] + b1.x, 0.f) : 0.f);
        t[5] = __float2bfloat16(alive ? fmaxf(dn * s8[5] + b1.y, 0.f) : 0.f);
        t[6] = __float2bfloat16(alive ? fmaxf(dn * s8[6] + b1.z, 0.f) : 0.f);
        t[7] = __float2bfloat16(alive ? fmaxf(dn * s8[7] + b1.w, 0.f) : 0.f);
        *(uint4*)&h_lds[wave * 4 + sub][cl * 8] = *(const uint4*)t;
    }
    __syncthreads();

    // ---- Phase B: 16x128 @ 128x128 MFMA; wave handles nt = {wave*2, wave*2+1} ----
    int m = cl, q = sub;
    bf16x8 a[4];
    #pragma unroll
    for (int kt = 0; kt < 4; ++kt)
        a[kt] = *(const bf16x8*)&h_lds[m][q * 8 + kt * 32];
    const bf16x8* bp = (const bf16x8*)Wsw;
    f32x4 g[2];
    g[0] = (f32x4){0.f, 0.f, 0.f, 0.f};
    g[1] = (f32x4){0.f, 0.f, 0.f, 0.f};
    #pragma unroll
    for (int kt = 0; kt < 4; ++kt) {
        #pragma unroll
        for (int j = 0; j < 2; ++j) {
            int nt = wave * 2 + j;
            bf16x8 bfr = bp[(size_t)(kt * 8 + nt) * 64 + lane];
            g[j] = __builtin_amdgcn_mfma_f32_16x16x32_bf16(a[kt], bfr, g[j], 0, 0, 0);
        }
    }
    #pragma unroll
    for (int j = 0; j < 2; ++j)
        #pragma unroll
        for (int r = 0; r < 4; ++r)
            s_out[(q * 4 + r) * 132 + (wave * 2 + j) * 16 + m] = g[j][r];
    __syncthreads();

    // ---- Phase C: coalesced, dis-pre-scaled bf16 store ----
    int on = threadIdx.x >> 4;
    int oc = (threadIdx.x & 15) * 8;
    if (base + on < N) {
        float ds = dis[base + on];
        const float* rp = s_out + on * 132 + oc;
        float4 v0 = *(const float4*)rp;
        float4 v1 = *(const float4*)(rp + 4);
        alignas(16) bf16 t[8] = {
            __float2bfloat16(v0.x * ds), __float2bfloat16(v0.y * ds),
            __float2bfloat16(v0.z * ds), __float2bfloat16(v0.w * ds),
            __float2bfloat16(v1.x * ds), __float2bfloat16(v1.y * ds),
            __float2bfloat16(v1.z * ds), __float2bfloat16(v1.w * ds)};
        *(uint4*)(Y2 + (size_t)(base + on) * DIM + oc) = *(const uint4*)t;
    }
}

// ================= K5: final aggregate (inputs pre-scaled) ==================
// 12-deep gather batches: more rows in flight per quarter-wave while staying
// under 128 VGPR (so launch_bounds(256,4) does not spill).
__global__ __launch_bounds__(256, 4)
void aggregate_final(const uint4* __restrict__ Y, const int* __restrict__ rowstart,
                     const int* __restrict__ cnt, const int* __restrict__ csr,
                     const float* __restrict__ dis, const float* __restrict__ bias,
                     float* __restrict__ Of, int N) {
    int wave = threadIdx.x >> 6;
    int lane = threadIdx.x & 63;
    int sub = lane >> 4, cl = lane & 15;
    int node = blockIdx.x * 16 + wave * 4 + sub;
    if (node >= N) return;
    int e0 = rowstart[node], e1 = e0 + cnt[node];

    float acc[4][8];
    #pragma unroll
    for (int j = 0; j < 4; ++j)
        #pragma unroll
        for (int k = 0; k < 8; ++k) acc[j][k] = 0.f;

    float dn = dis[node];
    add8(acc[3], Y[(size_t)node * 16 + cl]);            // self loop (pre-scaled)

    int e = e0;
    while (e + 12 <= e1) {
        int s[12];
        #pragma unroll
        for (int j = 0; j < 12; ++j) s[j] = csr[e + j];
        uint4 v[12];
        #pragma unroll
        for (int j = 0; j < 12; ++j) v[j] = Y[(size_t)s[j] * 16 + cl];
        #pragma unroll
        for (int j = 0; j < 12; ++j) add8(acc[j & 3], v[j]);
        e += 12;
    }
    if (e + 8 <= e1) {
        int s[8];
        #pragma unroll
        for (int j = 0; j < 8; ++j) s[j] = csr[e + j];
        uint4 v[8];
        #pragma unroll
        for (int j = 0; j < 8; ++j) v[j] = Y[(size_t)s[j] * 16 + cl];
        #pragma unroll
        for (int j = 0; j < 8; ++j) add8(acc[j & 3], v[j]);
        e += 8;
    }
    if (e + 4 <= e1) {
        int s[4];
        #pragma unroll
        for (int j = 0; j < 4; ++j) s[j] = csr[e + j];
        uint4 v[4];
        #pragma unroll
        for (int j = 0; j < 4; ++j) v[j] = Y[(size_t)s[j] * 16 + cl];
        #pragma unroll
        for (int j = 0; j < 4; ++j) add8(acc[j], v[j]);
        e += 4;
    }
    for (; e < e1; ++e)
        add8(acc[0], Y[(size_t)csr[e] * 16 + cl]);

    float s8[8];
    #pragma unroll
    for (int k = 0; k < 8; ++k)
        s8[k] = (acc[0][k] + acc[1][k]) + (acc[2][k] + acc[3][k]);

    float4 b0 = ((const float4*)bias)[2 * cl];
    float4 b1 = ((const float4*)bias)[2 * cl + 1];
    f32x4 o0, o1;
    o0[0] = fmaxf(dn * s8[0] + b0.x, 0.f);
    o0[1] = fmaxf(dn * s8[1] + b0.y, 0.f);
    o0[2] = fmaxf(dn * s8[2] + b0.z, 0.f);
    o0[3] = fmaxf(dn * s8[3] + b0.w, 0.f);
    o1[0] = fmaxf(dn * s8[4] + b1.x, 0.f);
    o1[1] = fmaxf(dn * s8[5] + b1.y, 0.f);
    o1[2] = fmaxf(dn * s8[6] + b1.z, 0.f);
    o1[3] = fmaxf(dn * s8[7] + b1.w, 0.f);
    // Output is never re-read: nontemporal keeps L2 clean for the Y2' gathers.
    f32x4* op = (f32x4*)(Of + (size_t)node * DIM + cl * 8);
    __builtin_nontemporal_store(o0, op);
    __builtin_nontemporal_store(o1, op + 1);
}

// ============================ launcher ======================================
extern "C" void kernel_launch(void* const* d_in, const int* in_sizes, int n_in,
                              void* d_out, int out_size, void* d_ws, size_t ws_size,
                              hipStream_t stream) {
    const float* x  = (const float*)d_in[0];
    const int*   ei = (const int*)d_in[1];
    const float* W1 = (const float*)d_in[2];
    const float* b1 = (const float*)d_in[3];
    const float* W2 = (const float*)d_in[4];
    const float* b2 = (const float*)d_in[5];

    int N = in_sizes[0] / DIM;      // 50000
    int E = in_sizes[1] / 2;        // 600000
    int nbuck = (N + 127) / 128;    // 391
    int nchunks = (E + CHUNK - 1) / CHUNK;  // 147

    char* w = (char*)d_ws;
    size_t used = 0;
    auto carve = [&](size_t bytes) {
        char* p = w + used;
        used += (bytes + 255) & ~(size_t)255;
        return p;
    };
    int*      misc     = (int*)     carve(256);              // [1]=flagI
    int*      bcursor  = (int*)     carve((size_t)(nbuck + 1) * 4);
    unsigned* staged   = (unsigned*)carve((size_t)nbuck * CAP * 4);   // 6.4 MB
    int*      csr      = (int*)     carve((size_t)nbuck * CAP * 4);   // 6.4 MB
    int*      rowstart = (int*)     carve((size_t)N * 4);
    int*      cnt      = (int*)     carve((size_t)N * 4);
    float*    dis      = (float*)   carve((size_t)N * 4);
    bf16*     ybuf     = (bf16*)    carve((size_t)N * DIM * 2);       // Y1
    bf16*     hbuf     = (bf16*)    carve((size_t)N * DIM * 2);       // Y2' (pre-scaled)
    bf16*     Wsw1     = (bf16*)    carve((size_t)DIM * DIM * 2);
    bf16*     Wsw2     = (bf16*)    carve((size_t)DIM * DIM * 2);

    prep_kernel <<<18, 256, 0, stream>>>(bcursor, nbuck, ei, E, misc, W1, W2, Wsw1, Wsw2);
    // 196 gemm blocks -> ~4 tiles/wave so the register-preloaded W is reused.
    scatter_gemm1<<<nchunks + 196, 256, 0, stream>>>(ei, E, misc, bcursor, staged,
                                                     nbuck, nchunks, x, Wsw1, ybuf, N);
    bucket_sort <<<nbuck, 256, 0, stream>>>(staged, bcursor, csr, rowstart, cnt, dis, N);

    int ablocks = (N + 15) / 16;            // 3125
    agg1_gemm2<<<ablocks, 256, 0, stream>>>((const uint4*)ybuf, rowstart, cnt, csr,
                                            dis, b1, Wsw2, hbuf, N);
    aggregate_final<<<ablocks, 256, 0, stream>>>((const uint4*)hbuf, rowstart, cnt, csr,
                                                 dis, b2, (float*)d_out, N);
}